// Round 17
// baseline (188.028 us; speedup 1.0000x reference)
//
#include <hip/hip_runtime.h>

#define TT 512

typedef _Float16 f16x8 __attribute__((ext_vector_type(8)));
typedef float f32x4 __attribute__((ext_vector_type(4)));

__device__ __forceinline__ float fast_exp2(float v) { return __builtin_amdgcn_exp2f(v); }
__device__ __forceinline__ float fast_rcp(float v)  { return __builtin_amdgcn_rcpf(v); }

__global__ __launch_bounds__(64, 1) void lstm_ls4c_kernel(
    const float* __restrict__ x,     // [B, T, 1]
    const float* __restrict__ wih,   // [128, 1]
    const float* __restrict__ whh,   // [128, 32]
    const float* __restrict__ bih,   // [128]
    const float* __restrict__ bhh,   // [128]
    const float* __restrict__ fc1w,  // [16, 32]
    const float* __restrict__ fc1b,  // [16]
    const float* __restrict__ fc2w,  // [1, 16]
    const float* __restrict__ fc2b,  // [1]
    float* __restrict__ out)         // [B, 1]
{
    __shared__ float lds_xT[TT + 2][4];   // x transposed [t][batch 0..3]; rows TT,TT+1 zeroed
    __shared__ float lds_hf[4][32];       // final h f32 for MLP head

    const int lane = threadIdx.x;         // single wave per block
    const int b0 = blockIdx.x * 4;        // 4 real batches per block
    const int c  = lane & 15;             // MFMA col; real batch = c&3
    const int cb = c & 3;
    const int g  = c >> 2;                // col-group 0..3 — owns acc row r == g
    const int q  = lane >> 4;             // k-group / C row-group

    // ---- stage x rows b0..b0+3 transposed into LDS ----
    {
        const int rb = lane >> 4;         // batch 0..3
        const int m  = lane & 15;
        const float4* xr = reinterpret_cast<const float4*>(x + (size_t)(b0 + rb) * TT);
#pragma unroll
        for (int it = 0; it < 8; ++it) {
            const int idx = it * 16 + m;  // float4 index 0..127
            const float4 v = xr[idx];
            const int t0 = idx * 4;
            lds_xT[t0 + 0][rb] = v.x;
            lds_xT[t0 + 1][rb] = v.y;
            lds_xT[t0 + 2][rb] = v.z;
            lds_xT[t0 + 3][rb] = v.w;
        }
        if (lane < 8) lds_xT[TT + (lane >> 2)][lane & 3] = 0.0f;
    }

    const float NK  = -1.4426950408889634f;   // -log2(e)
    const float NK2 = -2.8853900817779268f;   // -2*log2(e)

    // ---- A fragments, GLOBAL sigma k-order: k-slot 8q+2s+p <-> unit 4q+s+16p ----
    f16x8 afrag[8];
#pragma unroll
    for (int n = 0; n < 8; ++n) {
        const float s = (n == 4 || n == 5) ? NK2 : NK;
        const float* src = whh + (n * 16 + c) * 32;
        f16x8 a;
#pragma unroll
        for (int j = 0; j < 8; ++j)
            a[j] = (_Float16)(s * src[4 * q + (j >> 1) + 16 * (j & 1)]);
        afrag[n] = a;
    }

    // ---- hoisted MFMA C-init: scaled bias for rows 4q+r (all r; each lane
    // consumes r==g, other rows are the correct bias for their consumer lanes) ----
    f32x4 cinit[8];
#pragma unroll
    for (int n = 0; n < 8; ++n) {
        const float s = (n == 4 || n == 5) ? NK2 : NK;
#pragma unroll
        for (int r = 0; r < 4; ++r) {
            const int gg = n * 16 + q * 4 + r;
            cinit[n][r] = s * (bih[gg] + bhh[gg]);
        }
    }

    // ---- scaled wih for OWN gate row only: gg = 16n + 4q + g ----
    float wq[8];
#pragma unroll
    for (int n = 0; n < 8; ++n) {
        const float s = (n == 4 || n == 5) ? NK2 : NK;
        wq[n] = s * wih[n * 16 + q * 4 + g];
    }

    // bpermute byte-addresses for bfrag words s=0..3: source lane (c&3) + 4s + 16q
    const int ba0 = 4 * (cb + 0  + 16 * q);
    const int ba1 = 4 * (cb + 4  + 16 * q);
    const int ba2 = 4 * (cb + 8  + 16 * q);
    const int ba3 = 4 * (cb + 12 + 16 * q);

    f16x8 bfrag;
#pragma unroll
    for (int j = 0; j < 8; ++j) bfrag[j] = (_Float16)0.0f;

    float cs0 = 0.0f, cs1 = 0.0f;         // c-state: units 4q+g (p=0), 4q+g+16 (p=1)
    const bool gl = (g & 1) != 0;
    const bool gh = (g & 2) != 0;

    float xv = lds_xT[0][cb];             // same-wave DS ordering; no barrier needed

#pragma unroll 2
    for (int t = 0; t < TT; ++t) {
        f32x4 acc[8];
#pragma unroll
        for (int n = 0; n < 8; ++n)
            acc[n] = __builtin_amdgcn_mfma_f32_16x16x32_f16(afrag[n], bfrag, cinit[n], 0, 0, 0);

        const float xnext = lds_xT[t + 1][cb];

        // extract own row r=g (3 cndmask) + single fma fold of x·wih
        float v0, v1, v2, v3, v4, v5, v6, v7;
        {
            float lo, hi;
            lo = gl ? acc[0][1] : acc[0][0]; hi = gl ? acc[0][3] : acc[0][2];
            v0 = __builtin_fmaf(xv, wq[0], gh ? hi : lo);
            lo = gl ? acc[1][1] : acc[1][0]; hi = gl ? acc[1][3] : acc[1][2];
            v1 = __builtin_fmaf(xv, wq[1], gh ? hi : lo);
            lo = gl ? acc[2][1] : acc[2][0]; hi = gl ? acc[2][3] : acc[2][2];
            v2 = __builtin_fmaf(xv, wq[2], gh ? hi : lo);
            lo = gl ? acc[3][1] : acc[3][0]; hi = gl ? acc[3][3] : acc[3][2];
            v3 = __builtin_fmaf(xv, wq[3], gh ? hi : lo);
            lo = gl ? acc[4][1] : acc[4][0]; hi = gl ? acc[4][3] : acc[4][2];
            v4 = __builtin_fmaf(xv, wq[4], gh ? hi : lo);
            lo = gl ? acc[5][1] : acc[5][0]; hi = gl ? acc[5][3] : acc[5][2];
            v5 = __builtin_fmaf(xv, wq[5], gh ? hi : lo);
            lo = gl ? acc[6][1] : acc[6][0]; hi = gl ? acc[6][3] : acc[6][2];
            v6 = __builtin_fmaf(xv, wq[6], gh ? hi : lo);
            lo = gl ? acc[7][1] : acc[7][0]; hi = gl ? acc[7][3] : acc[7][2];
            v7 = __builtin_fmaf(xv, wq[7], gh ? hi : lo);
        }

        // breadth-first: all 8 gate exp2 back-to-back (trans pipe pipelines)
        const float ei0 = fast_exp2(v0);
        const float ei1 = fast_exp2(v1);
        const float ef0 = fast_exp2(v2);
        const float ef1 = fast_exp2(v3);
        const float eg0 = fast_exp2(v4);
        const float eg1 = fast_exp2(v5);
        const float eo0 = fast_exp2(v6);
        const float eo1 = fast_exp2(v7);

        // cell algebra, p=0 and p=1 interleaved (independent chains)
        const float P0  = (1.0f + ei0) * (1.0f + eg0);
        const float P1  = (1.0f + ei1) * (1.0f + eg1);
        const float Bf0 = 1.0f + ef0;
        const float Bf1 = 1.0f + ef1;
        const float N0  = __builtin_fmaf(cs0, P0, (1.0f - eg0) * Bf0);
        const float N1  = __builtin_fmaf(cs1, P1, (1.0f - eg1) * Bf1);
        const float D0  = P0 * Bf0;
        const float D1  = P1 * Bf1;
        const float rd  = fast_rcp(D0 * D1);
        const float cn0 = N0 * (rd * D1);
        const float cn1 = N1 * (rd * D0);
        cs0 = cn0; cs1 = cn1;

        const float ec0 = fast_exp2(NK2 * cn0);
        const float ec1 = fast_exp2(NK2 * cn1);
        const float dn0 = (1.0f + eo0) * (1.0f + ec0);
        const float dn1 = (1.0f + eo1) * (1.0f + ec1);
        const float rd2 = fast_rcp(dn0 * dn1);
        const float hv0 = (1.0f - ec0) * (rd2 * dn1);
        const float hv1 = (1.0f - ec1) * (rd2 * dn0);

        // pack own word (bfrag slot g) and gather all 4 slots via bpermute
        const int w = (int)__builtin_bit_cast(unsigned, __builtin_amdgcn_cvt_pkrtz(hv0, hv1));
        uint4 bw;
        bw.x = (unsigned)__builtin_amdgcn_ds_bpermute(ba0, w);
        bw.y = (unsigned)__builtin_amdgcn_ds_bpermute(ba1, w);
        bw.z = (unsigned)__builtin_amdgcn_ds_bpermute(ba2, w);
        bw.w = (unsigned)__builtin_amdgcn_ds_bpermute(ba3, w);
        bfrag = __builtin_bit_cast(f16x8, bw);

        xv = xnext;
    }

    // ---- final h to LDS: bfrag[2s+p] = h(unit 4q+s+16p) of batch c&3 ----
    if (c < 4) {
#pragma unroll
        for (int j = 0; j < 8; ++j)
            lds_hf[c][4 * q + (j >> 1) + 16 * (j & 1)] = (float)bfrag[j];
    }

    // same-wave write->read, in order; no barrier needed
    const int bat = lane >> 4;            // 16 lanes per batch
    const int m   = lane & 15;            // fc1 row
    float s = fc1b[m];
    const float* fw = fc1w + m * 32;
#pragma unroll 8
    for (int u = 0; u < 32; ++u) s = __builtin_fmaf(lds_hf[bat][u], fw[u], s);
    float val = fmaxf(s, 0.0f) * fc2w[m];
    val += __shfl_xor(val, 1);
    val += __shfl_xor(val, 2);
    val += __shfl_xor(val, 4);
    val += __shfl_xor(val, 8);
    if (m == 0) out[b0 + bat] = val + fc2b[0];
}

extern "C" void kernel_launch(void* const* d_in, const int* in_sizes, int n_in,
                              void* d_out, int out_size, void* d_ws, size_t ws_size,
                              hipStream_t stream) {
    const float* x    = (const float*)d_in[0];
    const float* wih  = (const float*)d_in[1];
    const float* whh  = (const float*)d_in[2];
    const float* bih  = (const float*)d_in[3];
    const float* bhh  = (const float*)d_in[4];
    const float* fc1w = (const float*)d_in[5];
    const float* fc1b = (const float*)d_in[6];
    const float* fc2w = (const float*)d_in[7];
    const float* fc2b = (const float*)d_in[8];
    float* out = (float*)d_out;

    const int B = out_size;               // 4096
    dim3 grid(B / 4), block(64);          // 1024 one-wave chains -> 1 per SIMD
    hipLaunchKernelGGL(lstm_ls4c_kernel, grid, block, 0, stream,
                       x, wih, whh, bih, bhh, fc1w, fc1b, fc2w, fc2b, out);
}